// Round 8
// baseline (426.597 us; speedup 1.0000x reference)
//
#include <hip/hip_runtime.h>
#include <cstdint>
#include <cstddef>

// R13: R12 structure with (1) 512 blocks x 512 thr = 2 blocks/CU (4 waves/SIMD
// latency hiding; groups of 32 blocks x 16 jc-cols, XCD-local via XCC_ID
// registration -- 64 blocks/XCD forced by 61.5KB LDS + launch_bounds cap),
// (2) BLOCK-MAJOR h/P layouts: each block publishes contiguous full cache
// lines (kills the RFO-on-partial-line HBM fetches that stalled the vmcnt(0)
// barrier wait), (3) fresh step-indexed buffers kept (L1-staleness-proof).
// gi-in-registers pre-GEMM kept from R12. 2 launches: k0 + k2.

typedef __attribute__((ext_vector_type(8))) _Float16 f16x8;
typedef __attribute__((ext_vector_type(4))) float floatx4;

__device__ unsigned g_cnt[8 * 64];     // per-XCD registration tickets (padded)
__device__ unsigned g_gbar[16 * 64];   // per-group barrier counters (padded)

// h[t]: [16 groups][32 cgrp][256 rows][16 cols] fp16 = 4 MB each.
// P[t]: [16 groups][32 cgrp][512] f32 = 1 MB each.
__device__ __align__(256) _Float16 g_h[12][16 * 32 * 256 * 16];
__device__ __align__(256) float    g_P[12][16 * 32 * 512];

__device__ __forceinline__ float sigm_f(float v) { return 1.0f / (1.0f + __expf(-v)); }
__device__ __forceinline__ float tanh_f(float v) { return 2.0f / (1.0f + __expf(-2.0f * v)) - 1.0f; }

__device__ __forceinline__ void async16(void* lds, const void* g) {
    __builtin_amdgcn_global_load_lds(
        (const __attribute__((address_space(1))) void*)g,
        (__attribute__((address_space(3))) void*)lds, 16, 0, 0);
}

// Per-group barrier: EXACTLY 32 co-resident same-XCD blocks.
__device__ __forceinline__ void group_barrier32(unsigned gidx) {
    asm volatile("s_waitcnt vmcnt(0)" ::: "memory");
    __syncthreads();
    if (threadIdx.x == 0) {
        unsigned* ctr = &g_gbar[gidx * 64];
        unsigned t = __hip_atomic_fetch_add(ctr, 1u, __ATOMIC_RELAXED,
                                            __HIP_MEMORY_SCOPE_AGENT);
        unsigned target = (t & ~31u) + 32u;
        while (__hip_atomic_load(ctr, __ATOMIC_RELAXED,
                                 __HIP_MEMORY_SCOPE_AGENT) < target)
            __builtin_amdgcn_s_sleep(1);
    }
    __syncthreads();
}

// ---------------- K0: casts + packing + a0 (unchanged, validated) ----------------
__global__ __launch_bounds__(256) void k0_prep(
    const float* __restrict__ z, const float* __restrict__ x,
    const float* __restrict__ x0, const float* __restrict__ W_ia,
    const float* __restrict__ b_ia, const float* __restrict__ W_ih,
    const float* __restrict__ W_hh, const float* __restrict__ W_h0,
    const float* __restrict__ W_out, const float* __restrict__ b_hh,
    _Float16* __restrict__ zx16, _Float16* __restrict__ wcat16,
    _Float16* __restrict__ whh16, float* __restrict__ pk, float* __restrict__ xbuf)
{
    const int ZX = 4096 * 256, WC = 2048 * 256, WH = 1536 * 512, PKN = 512, XB = 4096 * 2;
    const int total = ZX + WC + WH + PKN + XB;
    for (int idx = blockIdx.x * 256 + threadIdx.x; idx < total; idx += gridDim.x * 256) {
        if (idx < ZX) {
            int i = idx >> 8, k = idx & 255;
            float v = (k < 128) ? z[i * 128 + k] : x[i * 128 + (k - 128)];
            zx16[idx] = (_Float16)v;
        } else if (idx < ZX + WC) {
            int j = idx - ZX;
            int n = j >> 8, k = j & 255;
            float v = (n < 512) ? W_h0[n * 256 + k] : W_ih[(n - 512) * 258 + k];
            wcat16[j] = (_Float16)v;
        } else if (idx < ZX + WC + WH) {
            int j = idx - ZX - WC;
            whh16[j] = (_Float16)W_hh[j];
        } else if (idx < ZX + WC + WH + PKN) {
            int jc = idx - ZX - WC - WH;
            float* o = pk + jc * 12;
            o[0] = W_ih[jc * 258 + 256];          o[1] = W_ih[jc * 258 + 257];
            o[2] = W_ih[(512 + jc) * 258 + 256];  o[3] = W_ih[(512 + jc) * 258 + 257];
            o[4] = W_ih[(1024 + jc) * 258 + 256]; o[5] = W_ih[(1024 + jc) * 258 + 257];
            o[6] = b_hh[jc]; o[7] = b_hh[512 + jc]; o[8] = b_hh[1024 + jc];
            o[9] = W_out[jc]; o[10] = W_out[512 + jc]; o[11] = 0.f;
        } else {
            int j = idx - ZX - WC - WH - PKN;
            int i = j >> 1, d = j & 1;
            float s = b_ia[d];
            #pragma unroll
            for (int k2 = 0; k2 < 4; k2++) s += x0[i * 4 + k2] * W_ia[d * 4 + k2];
            xbuf[j] = s;
        }
    }
}

// ---------------- K2: fused pre-GEMM + XCD-local persistent GRU, 2 blk/CU ----------------
// Block = 16 jc-cols x 3 gates for one 256-sample group. LDS: B @0 (48KB:
// 48 rows x 1024B; pre-phase 64 rows x 512B), hstore[256][16]h @49152 (8KB),
// xs[256][2]f @57344, oac[256][2]f @59392, slot @61440. Total 61504.
__global__ __launch_bounds__(512, 4) void k2_fused(
    const _Float16* __restrict__ zx16, const _Float16* __restrict__ wcat16,
    const _Float16* __restrict__ whh16, const float* __restrict__ pk,
    const float* __restrict__ xbuf, const float* __restrict__ b_h0,
    const float* __restrict__ b_ih, float* __restrict__ dout,
    const float* __restrict__ b_out)
{
    extern __shared__ __align__(16) char smem[];
    const uint32_t BOFF = 0, HST = 49152, XSO = 57344, OAC = 59392, SLO = 61440;
    const int tid = threadIdx.x;
    float* xs  = (float*)(smem + XSO);
    float* oacf = (float*)(smem + OAC);

    // ---- XCD discovery + registration (2 blk/CU => exactly 64 blks/XCD) ----
    unsigned xcc;
    asm volatile("s_getreg_b32 %0, hwreg(HW_REG_XCC_ID)" : "=s"(xcc));
    xcc &= 7u;
    if (tid == 0) {
        unsigned s = __hip_atomic_fetch_add(&g_cnt[xcc * 64], 1u, __ATOMIC_RELAXED,
                                            __HIP_MEMORY_SCOPE_AGENT) & 63u;
        *(unsigned*)(smem + SLO) = s;
    }
    __syncthreads();
    const unsigned slot = *(volatile unsigned*)(smem + SLO);
    const int shalf = slot >> 5, cgrp = slot & 31;
    const unsigned gidx = xcc * 2 + shalf;      // 0..15, 32 blocks each
    const int M0g = (int)gidx * 256;            // group's global sample base
    const int jc0 = cgrp * 16;                  // block's 16 h-cols (x3 gates)

    const int wv = tid >> 6, lane = tid & 63;
    const int l15 = lane & 15, q2 = lane >> 4;

    // ---- stage pre-B: 64 rows x 256 fp16 (512B) from wcat16, swizzled ----
    // rows 0..47: W_ih gate rows (g=r>>4, jin=r&15 -> wcat 512+g*512+jc0+jin)
    // rows 48..63: W_h0 rows (wcat jc0 + (r-48)). Two rows per async16.
    {
        #pragma unroll
        for (int j2 = 0; j2 < 4; j2++) {
            int p = j2 * 8 + wv;              // 0..31 (wave-uniform)
            int r0 = p * 2;
            int r = r0 + (lane >> 5);
            int s = lane & 31;
            int n = (r < 48) ? (512 + (r >> 4) * 512 + jc0 + (r & 15))
                             : (jc0 + (r - 48));
            const _Float16* src = wcat16 + (size_t)n * 256 + ((s ^ (r & 15)) << 3);
            async16(smem + (uint32_t)r0 * 512, src);
        }
    }

    // ---- t-invariant params (single 16-col slice) ----
    const int jc = jc0 + l15;
    const float4* pkp = (const float4*)(pk + (size_t)jc * 12);
    float4 p0v = pkp[0], p1v = pkp[1], p2v = pkp[2];
    float wo0 = p2v.y, wo1 = p2v.z;
    float bh0 = b_h0[jc];
    float bih0 = b_ih[jc], bih1 = b_ih[512 + jc], bih2 = b_ih[1024 + jc];

    // step-B read bases (48 rows x 1024B, validated swizzle family)
    uint32_t bbase[3];
    #pragma unroll
    for (int g = 0; g < 3; g++) {
        int r = g * 16 + l15;
        bbase[g] = BOFF + (uint32_t)r * 1024 +
                   ((uint32_t)(q2 ^ (r & 3)) << 4) +
                   ((uint32_t)((r >> 2) & 3) << 6);
    }
    // pre-GEMM B read bases (64 rows x 512B): slots 0..2 gi, 3 h0
    uint32_t pb[4];
    #pragma unroll
    for (int sl = 0; sl < 4; sl++) {
        int r = (sl < 3) ? (sl * 16 + l15) : (48 + l15);
        pb[sl] = BOFF + (uint32_t)r * 512 +
                 ((uint32_t)(q2 ^ (r & 3)) << 4) +
                 ((uint32_t)((r >> 2) & 3) << 6);
    }
    __syncthreads();   // pre-B staged (barrier drains vmcnt)

    // ---- pre-GEMM: K=256, A=zx16 (sample-major, 512B rows), 8 ks ----
    floatx4 accP[2][4];
    #pragma unroll
    for (int mt = 0; mt < 2; mt++)
        #pragma unroll
        for (int sl = 0; sl < 4; sl++) accP[mt][sl] = (floatx4){0.f, 0.f, 0.f, 0.f};
    {
        const char* zp0 = (const char*)zx16 +
            ((size_t)(M0g + (wv * 2 + 0) * 16 + l15) * 512) + (size_t)q2 * 16;
        const char* zp1 = (const char*)zx16 +
            ((size_t)(M0g + (wv * 2 + 1) * 16 + l15) * 512) + (size_t)q2 * 16;
        f16x8 aq[2][2];
        #define ALOADZ(S, KS) do { \
            aq[S][0] = *(const f16x8*)(zp0 + (KS) * 64); \
            aq[S][1] = *(const f16x8*)(zp1 + (KS) * 64); \
        } while (0)
        ALOADZ(0, 0); ALOADZ(1, 1);
        #pragma unroll
        for (int ks = 0; ks < 8; ks++) {
            f16x8 a0 = aq[ks & 1][0];
            f16x8 a1 = aq[ks & 1][1];
            if (ks < 6) { ALOADZ(ks & 1, ks + 2); }
            const uint32_t kadd = (uint32_t)((ks >> 2) << 8);
            const uint32_t kxor = (uint32_t)((ks & 3) << 6);
            #pragma unroll
            for (int sl = 0; sl < 4; sl++) {
                f16x8 b = *(const f16x8*)(smem + ((pb[sl] + kadd) ^ kxor));
                accP[0][sl] = __builtin_amdgcn_mfma_f32_16x16x32_f16(a0, b, accP[0][sl], 0, 0, 0);
                accP[1][sl] = __builtin_amdgcn_mfma_f32_16x16x32_f16(a1, b, accP[1][sl], 0, 0, 0);
            }
        }
        #undef ALOADZ
    }

    // ---- gi -> registers (+bias); h0 -> hstore ----
    float gi[2][3][4];
    #pragma unroll
    for (int mt = 0; mt < 2; mt++)
        #pragma unroll
        for (int reg = 0; reg < 4; reg++) {
            gi[mt][0][reg] = accP[mt][0][reg] + bih0;
            gi[mt][1][reg] = accP[mt][1][reg] + bih1;
            gi[mt][2][reg] = accP[mt][2][reg] + bih2;
        }
    #pragma unroll
    for (int mt = 0; mt < 2; mt++)
        #pragma unroll
        for (int reg = 0; reg < 4; reg++) {
            int rl = (wv * 2 + mt) * 16 + q2 * 4 + reg;
            float v = accP[mt][3][reg] + bh0;
            *(_Float16*)(smem + HST + (uint32_t)(rl * 16 + l15) * 2) = (_Float16)v;
        }
    __syncthreads();

    // ---- stage W_hh (48 rows x 512, 48KB) ----
    {
        #pragma unroll
        for (int j = 0; j < 6; j++) {
            int r = j * 8 + wv;               // 0..47
            int n = (r >> 4) * 512 + jc0 + (r & 15);
            const _Float16* src = whh16 + (size_t)n * 512 + ((lane ^ (r & 15)) << 3);
            async16(smem + BOFF + (uint32_t)r * 1024, src);
        }
    }
    // ---- publish h0 slice: 16B/thread, block-contiguous (full lines) ----
    {
        int row = tid >> 1, ch = (tid & 1) * 8;
        f16x8 hv = *(const f16x8*)(smem + HST + (uint32_t)(row * 16 + ch) * 2);
        *(f16x8*)(&g_h[0][0] + ((size_t)(gidx * 32 + cgrp) * 256 + row) * 16 + ch) = hv;
    }
    group_barrier32(gidx);   // drains whh staging + h0 publish

    // A-read slab base for the block-major h layout (t-invariant part):
    // addr(ks,mt) = gbase + (q2>>1)*8192 + row*32 + (q2&1)*16 + ks*16384
    const size_t abase = (size_t)gidx * 262144 + (size_t)(q2 >> 1) * 8192 + (size_t)(q2 & 1) * 16;
    const size_t ar0 = abase + (size_t)((wv * 2 + 0) * 16 + l15) * 32;
    const size_t ar1 = abase + (size_t)((wv * 2 + 1) * 16 + l15) * 32;

    // ---- 12-step loop ----
    #pragma unroll 1
    for (int t = 0; t < 12; t++) {
        const char* hcur = (const char*)&g_h[t][0];

        // ---- GEMM: K=512, 16 ks, depth-2 A queue ----
        const char* rp0 = hcur + ar0;
        const char* rp1 = hcur + ar1;
        floatx4 acc[2][3];
        #pragma unroll
        for (int mt = 0; mt < 2; mt++)
            #pragma unroll
            for (int g = 0; g < 3; g++)
                acc[mt][g] = (floatx4){0.f, 0.f, 0.f, 0.f};

        f16x8 aq[2][2];
        #define ALOAD(S, KS) do { \
            aq[S][0] = *(const f16x8*)(rp0 + (size_t)(KS) * 16384); \
            aq[S][1] = *(const f16x8*)(rp1 + (size_t)(KS) * 16384); \
        } while (0)
        ALOAD(0, 0); ALOAD(1, 1);
        #pragma unroll
        for (int ks = 0; ks < 16; ks++) {
            f16x8 a0 = aq[ks & 1][0];
            f16x8 a1 = aq[ks & 1][1];
            if (ks < 14) { ALOAD(ks & 1, ks + 2); }
            const uint32_t kadd = (uint32_t)((ks >> 2) << 8);
            const uint32_t kxor = (uint32_t)((ks & 3) << 6);
            #pragma unroll
            for (int g = 0; g < 3; g++) {
                f16x8 b = *(const f16x8*)(smem + ((bbase[g] + kadd) ^ kxor));
                acc[0][g] = __builtin_amdgcn_mfma_f32_16x16x32_f16(a0, b, acc[0][g], 0, 0, 0);
                acc[1][g] = __builtin_amdgcn_mfma_f32_16x16x32_f16(a1, b, acc[1][g], 0, 0, 0);
            }
        }
        #undef ALOAD

        // ---- prologue after GEMM: x_t (+ dout_{t-1}) ----
        {
            int i = tid >> 1, d = tid & 1;
            float v;
            if (t == 0) {
                v = xbuf[(size_t)(M0g + i) * 2 + d];
            } else {
                const float* pp = &g_P[t - 1][0] + (size_t)gidx * 16384 + tid;
                float s = b_out[d];
                #pragma unroll
                for (int c = 0; c < 32; c++) s += pp[(size_t)c * 512];
                if (cgrp == 0) dout[((size_t)(M0g + i) * 12 + (t - 1)) * 2 + d] = s;
                v = s;
            }
            xs[tid] = v;
        }
        __syncthreads();

        // ---- epilogue: gates (gi in regs), hn -> hstore, out-partials ----
        float po[2][4][2];
        #pragma unroll
        for (int mt = 0; mt < 2; mt++)
            #pragma unroll
            for (int reg = 0; reg < 4; reg++) { po[mt][reg][0] = 0.f; po[mt][reg][1] = 0.f; }

        #pragma unroll
        for (int mt = 0; mt < 2; mt++) {
            #pragma unroll
            for (int reg = 0; reg < 4; reg++) {
                int rl = (wv * 2 + mt) * 16 + q2 * 4 + reg;   // local row 0..255
                float x0v = xs[rl * 2], x1v = xs[rl * 2 + 1];
                _Float16* hp = (_Float16*)(smem + HST + (uint32_t)(rl * 16 + l15) * 2);
                float hold = (float)hp[0];
                float r  = sigm_f(gi[mt][0][reg] + p0v.x * x0v + p0v.y * x1v + acc[mt][0][reg] + p1v.z);
                float u  = sigm_f(gi[mt][1][reg] + p0v.z * x0v + p0v.w * x1v + acc[mt][1][reg] + p1v.w);
                float nn = tanh_f(gi[mt][2][reg] + p1v.x * x0v + p1v.y * x1v + r * (acc[mt][2][reg] + p2v.x));
                float hn = (1.f - u) * nn + u * hold;
                hp[0] = (_Float16)hn;
                po[mt][reg][0] += hn * wo0;
                po[mt][reg][1] += hn * wo1;
            }
        }
        #pragma unroll
        for (int m = 1; m < 16; m <<= 1)
            #pragma unroll
            for (int mt = 0; mt < 2; mt++)
                #pragma unroll
                for (int reg = 0; reg < 4; reg++) {
                    po[mt][reg][0] += __shfl_xor(po[mt][reg][0], m);
                    po[mt][reg][1] += __shfl_xor(po[mt][reg][1], m);
                }
        if (l15 == 0) {
            #pragma unroll
            for (int mt = 0; mt < 2; mt++)
                #pragma unroll
                for (int reg = 0; reg < 4; reg++) {
                    int rl = (wv * 2 + mt) * 16 + q2 * 4 + reg;
                    ((float2*)oacf)[rl] = make_float2(po[mt][reg][0], po[mt][reg][1]);
                }
        }
        __syncthreads();   // hstore + oacf complete across waves

        // ---- publish h (t<11) + partials: block-contiguous full-line stores ----
        if (t < 11) {
            int row = tid >> 1, ch = (tid & 1) * 8;
            f16x8 hv = *(const f16x8*)(smem + HST + (uint32_t)(row * 16 + ch) * 2);
            *(f16x8*)(&g_h[t + 1][0] + ((size_t)(gidx * 32 + cgrp) * 256 + row) * 16 + ch) = hv;
        }
        g_P[t][(size_t)(gidx * 32 + cgrp) * 512 + tid] = oacf[tid];
        group_barrier32(gidx);
    }

    // ---- final output out_11 ----
    if (cgrp == 0) {
        int i = tid >> 1, d = tid & 1;
        const float* pp = &g_P[11][0] + (size_t)gidx * 16384 + tid;
        float s = b_out[d];
        #pragma unroll
        for (int c = 0; c < 32; c++) s += pp[(size_t)c * 512];
        dout[((size_t)(M0g + i) * 12 + 11) * 2 + d] = s;
    }
}

extern "C" void kernel_launch(void* const* d_in, const int* in_sizes, int n_in,
                              void* d_out, int out_size, void* d_ws, size_t ws_size,
                              hipStream_t stream)
{
    const float* z     = (const float*)d_in[0];
    const float* x     = (const float*)d_in[1];
    const float* x0    = (const float*)d_in[2];
    const float* W_ia  = (const float*)d_in[3];
    const float* b_ia  = (const float*)d_in[4];
    const float* W_h0  = (const float*)d_in[5];
    const float* b_h0  = (const float*)d_in[6];
    const float* W_ih  = (const float*)d_in[7];
    const float* b_ih  = (const float*)d_in[8];
    const float* W_hh  = (const float*)d_in[9];
    const float* b_hh  = (const float*)d_in[10];
    const float* W_out = (const float*)d_in[11];
    const float* b_out = (const float*)d_in[12];
    float* dout = (float*)d_out;

    char* ws = (char*)d_ws;
    _Float16* zx16   = (_Float16*)(ws + 20971520);   // 2 MiB
    _Float16* wcat16 = (_Float16*)(ws + 23068672);   // 1 MiB
    _Float16* whh16  = (_Float16*)(ws + 24117248);   // 1.5 MiB
    float*    pk     = (float*)(ws + 25690112);      // 24 KiB
    float*    xbuf   = (float*)(ws + 25714688);      // 32 KiB

    static bool s_attr_done = false;
    if (!s_attr_done) {
        hipFuncSetAttribute((const void*)k2_fused,
                            hipFuncAttributeMaxDynamicSharedMemorySize, 61504);
        s_attr_done = true;
    }

    k0_prep<<<2048, 256, 0, stream>>>(z, x, x0, W_ia, b_ia, W_ih, W_hh, W_h0,
                                      W_out, b_hh, zx16, wcat16, whh16, pk, xbuf);
    k2_fused<<<512, 512, 61504, stream>>>(zx16, wcat16, whh16, pk, xbuf,
                                          b_h0, b_ih, dout, b_out);
}